// Round 1
// baseline (1443.866 us; speedup 1.0000x reference)
//
#include <hip/hip_runtime.h>

// WarmStartSinkhornLinear on MI355X.
// out = x @ P.T with P = exp(Q + r + c) from 10 Sinkhorn iterations on Q = W/0.1.
// Strategy: f32 Sinkhorn (L3-resident passes), then bf16 MFMA GEMM (threshold is
// bf16-grade: 9.875e-2). Workspace layout (needs ~101 MB):
//   [0)              xb : 8192*4096 bf16 (67.1 MB)
//   [67108864)       Pb : 4096*4096 bf16 (33.5 MB)
//   [100663296)      rv : 4096 f32, then cv : 4096 f32

#define L2E 1.44269504088896340736f
#define LN2 0.69314718055994530942f

typedef __attribute__((ext_vector_type(8))) short bf16x8;
typedef __attribute__((ext_vector_type(4))) float f32x4;

__device__ __forceinline__ unsigned short f2bf(float x) {
  unsigned u = __float_as_uint(x);
  u += 0x7fffu + ((u >> 16) & 1u);  // RNE
  return (unsigned short)(u >> 16);
}

// ---- r[i] = -logsumexp_j(10*W[i,j] + c[j]); one block per row, 256 thr.
__global__ void row_lse(const float* __restrict__ W, const float* __restrict__ c,
                        float* __restrict__ r) {
  const int row = blockIdx.x;
  const int t = threadIdx.x;
  const float* wp = W + ((size_t)row << 12);
  float v[16];
  float m = -3.4e38f;
#pragma unroll
  for (int ch = 0; ch < 4; ++ch) {
    float4 wv = *(const float4*)(wp + ch * 1024 + t * 4);
    float4 cc = *(const float4*)(c + ch * 1024 + t * 4);
    float a0 = fmaf(10.f, wv.x, cc.x);
    float a1 = fmaf(10.f, wv.y, cc.y);
    float a2 = fmaf(10.f, wv.z, cc.z);
    float a3 = fmaf(10.f, wv.w, cc.w);
    v[ch * 4 + 0] = a0; v[ch * 4 + 1] = a1; v[ch * 4 + 2] = a2; v[ch * 4 + 3] = a3;
    m = fmaxf(m, fmaxf(fmaxf(a0, a1), fmaxf(a2, a3)));
  }
#pragma unroll
  for (int off = 32; off > 0; off >>= 1) m = fmaxf(m, __shfl_xor(m, off));
  __shared__ float sm[4], ss[4];
  if ((t & 63) == 0) sm[t >> 6] = m;
  __syncthreads();
  m = fmaxf(fmaxf(sm[0], sm[1]), fmaxf(sm[2], sm[3]));
  float s = 0.f;
#pragma unroll
  for (int k = 0; k < 16; ++k) s += exp2f((v[k] - m) * L2E);
#pragma unroll
  for (int off = 32; off > 0; off >>= 1) s += __shfl_xor(s, off);
  if ((t & 63) == 0) ss[t >> 6] = s;
  __syncthreads();
  if (t == 0) {
    float st = (ss[0] + ss[1]) + (ss[2] + ss[3]);
    r[row] = -fmaf(log2f(st), LN2, m);
  }
}

// ---- c[j] = -logsumexp_i(10*W[i,j] + r[i]); 256 blocks, 16 cols x 16 rowgroups.
__global__ void col_lse(const float* __restrict__ W, const float* __restrict__ r,
                        float* __restrict__ c) {
  const int t = threadIdx.x;
  const int col = (blockIdx.x << 4) + (t & 15);
  const int rg = t >> 4;  // 0..15
  float M = -3.4e38f, S = 0.f;
#pragma unroll 4
  for (int i = rg; i < 4096; i += 16) {
    float v = fmaf(10.f, W[((size_t)i << 12) + col], r[i]);
    if (v <= M) {
      S += exp2f((v - M) * L2E);
    } else {  // rare
      S = fmaf(S, exp2f((M - v) * L2E), 1.f);
      M = v;
    }
  }
  __shared__ float Ms[256], Ss[256];
  Ms[t] = M; Ss[t] = S;
  __syncthreads();
  if (t < 16) {
    float M0 = Ms[t], S0 = Ss[t];
#pragma unroll
    for (int k = 1; k < 16; ++k) {
      float M1 = Ms[t + (k << 4)], S1 = Ss[t + (k << 4)];
      float Mn = fmaxf(M0, M1);
      S0 = fmaf(S0, exp2f((M0 - Mn) * L2E), S1 * exp2f((M1 - Mn) * L2E));
      M0 = Mn;
    }
    c[(blockIdx.x << 4) + t] = -fmaf(log2f(S0), LN2, M0);
  }
}

// ---- Pb[n,k] = bf16(exp(10*W[n,k] + r[n] + c[k]))
__global__ void make_p(const float* __restrict__ W, const float* __restrict__ r,
                       const float* __restrict__ c, unsigned short* __restrict__ P) {
  const size_t idx = ((size_t)blockIdx.x * 256 + threadIdx.x) * 4;
  const int row = (int)(idx >> 12);
  const int col = (int)(idx & 4095);
  float4 wv = *(const float4*)(W + idx);
  float4 cc = *(const float4*)(c + col);
  float rr = r[row];
  ushort4 o;
  o.x = f2bf(exp2f((fmaf(10.f, wv.x, rr) + cc.x) * L2E));
  o.y = f2bf(exp2f((fmaf(10.f, wv.y, rr) + cc.y) * L2E));
  o.z = f2bf(exp2f((fmaf(10.f, wv.z, rr) + cc.z) * L2E));
  o.w = f2bf(exp2f((fmaf(10.f, wv.w, rr) + cc.w) * L2E));
  *(ushort4*)(P + idx) = o;
}

// ---- x f32 -> bf16
__global__ void cvt_bf16(const float* __restrict__ X, unsigned short* __restrict__ Y) {
  const size_t idx = ((size_t)blockIdx.x * 256 + threadIdx.x) * 4;
  float4 xv = *(const float4*)(X + idx);
  ushort4 o;
  o.x = f2bf(xv.x); o.y = f2bf(xv.y); o.z = f2bf(xv.z); o.w = f2bf(xv.w);
  *(ushort4*)(Y + idx) = o;
}

// ---- C[m,n] = sum_k A[m,k]*B[n,k]; A [8192,4096] bf16, B [4096,4096] bf16 (B^T GEMM).
// m97 structure: 128x128 tile, BK=32, 4 waves (2x2), 4x4 16x16x32 frags/wave,
// global_load_lds width 16, single-buffered 2-barrier K-loop.
__global__ __launch_bounds__(256) void gemm_bt(const unsigned short* __restrict__ A,
                                               const unsigned short* __restrict__ B,
                                               float* __restrict__ C) {
  __shared__ unsigned short As[128 * 32];
  __shared__ unsigned short Bs[128 * 32];
  const int t = threadIdx.x;
  const int l = t & 63;
  const int w = t >> 6;
  const int m0 = blockIdx.y << 7;
  const int n0 = blockIdx.x << 7;
  const int wr = w >> 1, wc = w & 1;
  f32x4 acc[4][4] = {};
  const int srow = l >> 2;          // 0..15 within a 16-row staging block
  const int scol = (l & 3) << 3;    // 0,8,16,24 (8 bf16 = 16B per lane)
  const unsigned short* Ab = A + ((size_t)m0 << 12);
  const unsigned short* Bb = B + ((size_t)n0 << 12);
  const int lrow = l & 15;
  const int lk = (l >> 4) << 3;

  for (int k0 = 0; k0 < 4096; k0 += 32) {
#pragma unroll
    for (int p = 0; p < 2; ++p) {
      const int rb = (p << 2) + w;  // 16-row block index 0..7
      const unsigned short* ga = Ab + (size_t)(rb * 16 + srow) * 4096 + k0 + scol;
      const unsigned short* gb = Bb + (size_t)(rb * 16 + srow) * 4096 + k0 + scol;
      __builtin_amdgcn_global_load_lds((const __attribute__((address_space(1))) void*)ga,
                                       (__attribute__((address_space(3))) void*)(As + rb * 512),
                                       16, 0, 0);
      __builtin_amdgcn_global_load_lds((const __attribute__((address_space(1))) void*)gb,
                                       (__attribute__((address_space(3))) void*)(Bs + rb * 512),
                                       16, 0, 0);
    }
    __syncthreads();
    bf16x8 af[4], bfr[4];
#pragma unroll
    for (int i = 0; i < 4; ++i) {
      af[i]  = *(const bf16x8*)(As + ((wr << 6) + (i << 4) + lrow) * 32 + lk);
      bfr[i] = *(const bf16x8*)(Bs + ((wc << 6) + (i << 4) + lrow) * 32 + lk);
    }
#pragma unroll
    for (int i = 0; i < 4; ++i)
#pragma unroll
      for (int j = 0; j < 4; ++j)
        acc[i][j] = __builtin_amdgcn_mfma_f32_16x16x32_bf16(af[i], bfr[j], acc[i][j], 0, 0, 0);
    __syncthreads();
  }

  const int crow = (l >> 4) << 2;
  const int ccol = l & 15;
#pragma unroll
  for (int i = 0; i < 4; ++i)
#pragma unroll
    for (int j = 0; j < 4; ++j)
#pragma unroll
      for (int q = 0; q < 4; ++q) {
        const int rowi = m0 + (wr << 6) + (i << 4) + crow + q;
        const int colj = n0 + (wc << 6) + (j << 4) + ccol;
        C[((size_t)rowi << 12) + colj] = acc[i][j][q];
      }
}

extern "C" void kernel_launch(void* const* d_in, const int* in_sizes, int n_in,
                              void* d_out, int out_size, void* d_ws, size_t ws_size,
                              hipStream_t stream) {
  const float* x      = (const float*)d_in[0];   // [4,2048,4096] f32
  const float* weight = (const float*)d_in[1];   // [4096,4096] f32
  const float* c_prev = (const float*)d_in[3];   // [1,4096] f32 (zeros); r_prev unused
  float* out = (float*)d_out;

  unsigned short* xb = (unsigned short*)d_ws;             // 8192*4096 bf16
  unsigned short* Pb = xb + (size_t)8192 * 4096;          // 4096*4096 bf16
  float* rv = (float*)(Pb + (size_t)4096 * 4096);
  float* cv = rv + 4096;

  // x -> bf16 (independent of Sinkhorn)
  cvt_bf16<<<32768, 256, 0, stream>>>(x, xb);

  for (int it = 0; it < 10; ++it) {
    row_lse<<<4096, 256, 0, stream>>>(weight, it == 0 ? c_prev : cv, rv);
    col_lse<<<256, 256, 0, stream>>>(weight, rv, cv);
  }

  make_p<<<16384, 256, 0, stream>>>(weight, rv, cv, Pb);

  gemm_bt<<<dim3(32, 64), 256, 0, stream>>>(xb, Pb, out);
}

// Round 2
// 516.523 us; speedup vs baseline: 2.7954x; 2.7954x over previous
//
#include <hip/hip_runtime.h>

// WarmStartSinkhornLinear on MI355X — round 2.
// out = x @ P.T, P = exp(Q + r + c), Q = 10*W, 10 Sinkhorn iters.
// Scaling-form Sinkhorn: E = exp(Q - rowmax) in bf16 (once), then
//   v = 1/(E u), u = 1/(E^T v)  x10   (u = e^c, v = e^{m+r})
// P = diag(v) E diag(u)  =>  A = bf16(x*u), B = E, epilogue *= v[col].
// Workspace layout (~100.7 MB):
//   [0)        u  : 4096 f32
//   [16K)      v  : 4096 f32
//   [64K)      E  : 4096*4096 bf16 (33.5 MB)
//   [64K+33.5M) ET : 4096*4096 bf16, later overlaid by xb : 8192*4096 bf16 (67 MB)

#define L2E 1.44269504088896340736f

typedef __attribute__((ext_vector_type(8))) short bf16x8;
typedef __attribute__((ext_vector_type(4))) float f32x4;

__device__ __forceinline__ unsigned short f2bf(float x) {
  unsigned u = __float_as_uint(x);
  u += 0x7fffu + ((u >> 16) & 1u);  // RNE
  return (unsigned short)(u >> 16);
}
__device__ __forceinline__ float bf2f(short x) {
  return __uint_as_float(((unsigned)(unsigned short)x) << 16);
}

// ---- E[row,:] = bf16(exp(10*W[row,:] - rowmax)); one block per row.
__global__ void prep_e(const float* __restrict__ W, unsigned short* __restrict__ E) {
  const int row = blockIdx.x;
  const int t = threadIdx.x;
  const float* wp = W + ((size_t)row << 12);
  float v[16];
  float m = -3.4e38f;
#pragma unroll
  for (int ch = 0; ch < 4; ++ch) {
    float4 wv = *(const float4*)(wp + ch * 1024 + t * 4);
    float a0 = 10.f * wv.x, a1 = 10.f * wv.y, a2 = 10.f * wv.z, a3 = 10.f * wv.w;
    v[ch * 4 + 0] = a0; v[ch * 4 + 1] = a1; v[ch * 4 + 2] = a2; v[ch * 4 + 3] = a3;
    m = fmaxf(m, fmaxf(fmaxf(a0, a1), fmaxf(a2, a3)));
  }
#pragma unroll
  for (int off = 32; off > 0; off >>= 1) m = fmaxf(m, __shfl_xor(m, off));
  __shared__ float sm[4];
  if ((t & 63) == 0) sm[t >> 6] = m;
  __syncthreads();
  m = fmaxf(fmaxf(sm[0], sm[1]), fmaxf(sm[2], sm[3]));
  unsigned short* ep = E + ((size_t)row << 12);
#pragma unroll
  for (int ch = 0; ch < 4; ++ch) {
    ushort4 o;
    o.x = f2bf(exp2f((v[ch * 4 + 0] - m) * L2E));
    o.y = f2bf(exp2f((v[ch * 4 + 1] - m) * L2E));
    o.z = f2bf(exp2f((v[ch * 4 + 2] - m) * L2E));
    o.w = f2bf(exp2f((v[ch * 4 + 3] - m) * L2E));
    *(ushort4*)(ep + ch * 1024 + t * 4) = o;
  }
}

// ---- ET[j][i] = E[i][j]; 64x64 bf16 tiles via LDS.
__global__ void transpose_bf(const unsigned short* __restrict__ E,
                             unsigned short* __restrict__ ET) {
  __shared__ unsigned short tile[64][66];
  const int t = threadIdx.x;
  const int r = t >> 3;          // 0..31
  const int c8 = (t & 7) << 3;   // 0,8,..,56
  const size_t i0 = (size_t)blockIdx.y << 6;
  const size_t j0 = (size_t)blockIdx.x << 6;
#pragma unroll
  for (int h = 0; h < 2; ++h) {
    bf16x8 vv = *(const bf16x8*)(E + (i0 + h * 32 + r) * 4096 + j0 + c8);
#pragma unroll
    for (int e = 0; e < 8; ++e) tile[h * 32 + r][c8 + e] = (unsigned short)vv[e];
  }
  __syncthreads();
#pragma unroll
  for (int h = 0; h < 2; ++h) {
    bf16x8 vv;
#pragma unroll
    for (int e = 0; e < 8; ++e) vv[e] = (short)tile[c8 + e][h * 32 + r];
    *(bf16x8*)(ET + (j0 + h * 32 + r) * 4096 + i0 + c8) = vv;
  }
}

// ---- u[i] = exp(c_prev[i])
__global__ void init_u(const float* __restrict__ c_prev, float* __restrict__ u) {
  const int i = blockIdx.x * 256 + threadIdx.x;
  u[i] = exp2f(c_prev[i] * L2E);
}

// ---- out[row] = 1 / sum_j M[row][j]*uin[j]; 1 wave per row, 4 rows/block.
__global__ void recip_mv(const unsigned short* __restrict__ M,
                         const float* __restrict__ uin, float* __restrict__ vout) {
  const int t = threadIdx.x;
  const int l = t & 63, w = t >> 6;
  const int row = (blockIdx.x << 2) + w;
  const unsigned short* mp = M + ((size_t)row << 12);
  float s = 0.f;
#pragma unroll
  for (int ch = 0; ch < 8; ++ch) {
    const int j = (ch << 9) + (l << 3);
    bf16x8 e = *(const bf16x8*)(mp + j);
    const float4 u0 = *(const float4*)(uin + j);
    const float4 u1 = *(const float4*)(uin + j + 4);
    s = fmaf(bf2f(e[0]), u0.x, s);
    s = fmaf(bf2f(e[1]), u0.y, s);
    s = fmaf(bf2f(e[2]), u0.z, s);
    s = fmaf(bf2f(e[3]), u0.w, s);
    s = fmaf(bf2f(e[4]), u1.x, s);
    s = fmaf(bf2f(e[5]), u1.y, s);
    s = fmaf(bf2f(e[6]), u1.z, s);
    s = fmaf(bf2f(e[7]), u1.w, s);
  }
#pragma unroll
  for (int off = 32; off > 0; off >>= 1) s += __shfl_xor(s, off);
  if (l == 0) vout[row] = 1.f / s;
}

// ---- xb[t,j] = bf16(x[t,j] * u[j])
__global__ void scale_x(const float* __restrict__ X, const float* __restrict__ u,
                        unsigned short* __restrict__ Y) {
  const size_t idx = ((size_t)blockIdx.x * 256 + threadIdx.x) * 4;
  const int col = (int)(idx & 4095);
  float4 xv = *(const float4*)(X + idx);
  float4 uu = *(const float4*)(u + col);
  ushort4 o;
  o.x = f2bf(xv.x * uu.x);
  o.y = f2bf(xv.y * uu.y);
  o.z = f2bf(xv.z * uu.z);
  o.w = f2bf(xv.w * uu.w);
  *(ushort4*)(Y + idx) = o;
}

// ---- C[m,n] = v[n] * sum_k A[m,k]*B[n,k]; A [8192,4096], B [4096,4096] bf16.
// m97 structure + bijective XCD swizzle + GROUP_M=8 tile mapping.
__global__ __launch_bounds__(256) void gemm_bt(const unsigned short* __restrict__ A,
                                               const unsigned short* __restrict__ B,
                                               const float* __restrict__ vscale,
                                               float* __restrict__ C) {
  __shared__ unsigned short As[128 * 32];
  __shared__ unsigned short Bs[128 * 32];
  int pid = blockIdx.x;                    // 0..2047
  pid = (pid & 7) * 256 + (pid >> 3);      // XCD-contiguous chunks (2048%8==0)
  const int g = pid >> 8;                  // 0..7
  const int rem = pid & 255;
  const int bm = (g << 3) + (rem & 7);     // 0..63
  const int bn = rem >> 3;                 // 0..31
  const int m0 = bm << 7;
  const int n0 = bn << 7;
  const int t = threadIdx.x;
  const int l = t & 63;
  const int w = t >> 6;
  const int wr = w >> 1, wc = w & 1;
  f32x4 acc[4][4] = {};
  const int srow = l >> 2;
  const int scol = (l & 3) << 3;
  const unsigned short* Ab = A + ((size_t)m0 << 12);
  const unsigned short* Bb = B + ((size_t)n0 << 12);
  const int lrow = l & 15;
  const int lk = (l >> 4) << 3;

  for (int k0 = 0; k0 < 4096; k0 += 32) {
#pragma unroll
    for (int p = 0; p < 2; ++p) {
      const int rb = (p << 2) + w;
      const unsigned short* ga = Ab + (size_t)(rb * 16 + srow) * 4096 + k0 + scol;
      const unsigned short* gb = Bb + (size_t)(rb * 16 + srow) * 4096 + k0 + scol;
      __builtin_amdgcn_global_load_lds((const __attribute__((address_space(1))) void*)ga,
                                       (__attribute__((address_space(3))) void*)(As + rb * 512),
                                       16, 0, 0);
      __builtin_amdgcn_global_load_lds((const __attribute__((address_space(1))) void*)gb,
                                       (__attribute__((address_space(3))) void*)(Bs + rb * 512),
                                       16, 0, 0);
    }
    __syncthreads();
    bf16x8 af[4], bfr[4];
#pragma unroll
    for (int i = 0; i < 4; ++i) {
      af[i]  = *(const bf16x8*)(As + ((wr << 6) + (i << 4) + lrow) * 32 + lk);
      bfr[i] = *(const bf16x8*)(Bs + ((wc << 6) + (i << 4) + lrow) * 32 + lk);
    }
#pragma unroll
    for (int i = 0; i < 4; ++i)
#pragma unroll
      for (int j = 0; j < 4; ++j)
        acc[i][j] = __builtin_amdgcn_mfma_f32_16x16x32_bf16(af[i], bfr[j], acc[i][j], 0, 0, 0);
    __syncthreads();
  }

  const int crow = (l >> 4) << 2;
  const int ccol = l & 15;
#pragma unroll
  for (int j = 0; j < 4; ++j) {
    const int colj = n0 + (wc << 6) + (j << 4) + ccol;
    const float vs = vscale[colj];
#pragma unroll
    for (int i = 0; i < 4; ++i)
#pragma unroll
      for (int q = 0; q < 4; ++q) {
        const int rowi = m0 + (wr << 6) + (i << 4) + crow + q;
        C[((size_t)rowi << 12) + colj] = acc[i][j][q] * vs;
      }
  }
}

extern "C" void kernel_launch(void* const* d_in, const int* in_sizes, int n_in,
                              void* d_out, int out_size, void* d_ws, size_t ws_size,
                              hipStream_t stream) {
  const float* x      = (const float*)d_in[0];   // [4,2048,4096] f32
  const float* weight = (const float*)d_in[1];   // [4096,4096] f32
  const float* c_prev = (const float*)d_in[3];   // [1,4096] f32; r_prev unused
  float* out = (float*)d_out;

  char* ws = (char*)d_ws;
  float* u = (float*)ws;                                   // 4096 f32
  float* v = (float*)(ws + (16 << 10));                    // 4096 f32
  unsigned short* E  = (unsigned short*)(ws + (64 << 10)); // 33.5 MB
  unsigned short* ET = E + (size_t)4096 * 4096;            // 33.5 MB (dead after iters)
  unsigned short* xb = ET;                                 // xb overlays ET (67 MB)

  prep_e<<<4096, 256, 0, stream>>>(weight, E);
  transpose_bf<<<dim3(64, 64), 256, 0, stream>>>(E, ET);
  init_u<<<16, 256, 0, stream>>>(c_prev, u);

  for (int it = 0; it < 10; ++it) {
    recip_mv<<<1024, 256, 0, stream>>>(E, u, v);   // v = 1/(E u)
    recip_mv<<<1024, 256, 0, stream>>>(ET, v, u);  // u = 1/(E^T v)
  }

  scale_x<<<32768, 256, 0, stream>>>(x, u, xb);    // xb = bf16(x * u), kills ET

  gemm_bt<<<2048, 256, 0, stream>>>(xb, E, v, out);
}

// Round 3
// 459.475 us; speedup vs baseline: 3.1424x; 1.1242x over previous
//
#include <hip/hip_runtime.h>

// WarmStartSinkhornLinear on MI355X — round 3.
// Scaling-form Sinkhorn (unchanged) + deep-pipelined 256x256 bf16 MFMA GEMM:
// BK=32, 8 waves, 4-buffer LDS ring, counted vmcnt(8) (never 0 in steady
// state), T2 chunk-XOR swizzle (conflict-free ds_read_b128), setprio around
// MFMA clusters, XCD-bijective block swizzle + GROUP_M=4.

#define L2E 1.44269504088896340736f

typedef __attribute__((ext_vector_type(8))) short bf16x8;
typedef __attribute__((ext_vector_type(4))) float f32x4;

__device__ __forceinline__ unsigned short f2bf(float x) {
  unsigned u = __float_as_uint(x);
  u += 0x7fffu + ((u >> 16) & 1u);  // RNE
  return (unsigned short)(u >> 16);
}
__device__ __forceinline__ float bf2f(short x) {
  return __uint_as_float(((unsigned)(unsigned short)x) << 16);
}

// ---- E[row,:] = bf16(exp(10*W[row,:] - rowmax)); one block per row.
__global__ void prep_e(const float* __restrict__ W, unsigned short* __restrict__ E) {
  const int row = blockIdx.x;
  const int t = threadIdx.x;
  const float* wp = W + ((size_t)row << 12);
  float v[16];
  float m = -3.4e38f;
#pragma unroll
  for (int ch = 0; ch < 4; ++ch) {
    float4 wv = *(const float4*)(wp + ch * 1024 + t * 4);
    float a0 = 10.f * wv.x, a1 = 10.f * wv.y, a2 = 10.f * wv.z, a3 = 10.f * wv.w;
    v[ch * 4 + 0] = a0; v[ch * 4 + 1] = a1; v[ch * 4 + 2] = a2; v[ch * 4 + 3] = a3;
    m = fmaxf(m, fmaxf(fmaxf(a0, a1), fmaxf(a2, a3)));
  }
#pragma unroll
  for (int off = 32; off > 0; off >>= 1) m = fmaxf(m, __shfl_xor(m, off));
  __shared__ float sm[4];
  if ((t & 63) == 0) sm[t >> 6] = m;
  __syncthreads();
  m = fmaxf(fmaxf(sm[0], sm[1]), fmaxf(sm[2], sm[3]));
  unsigned short* ep = E + ((size_t)row << 12);
#pragma unroll
  for (int ch = 0; ch < 4; ++ch) {
    ushort4 o;
    o.x = f2bf(exp2f((v[ch * 4 + 0] - m) * L2E));
    o.y = f2bf(exp2f((v[ch * 4 + 1] - m) * L2E));
    o.z = f2bf(exp2f((v[ch * 4 + 2] - m) * L2E));
    o.w = f2bf(exp2f((v[ch * 4 + 3] - m) * L2E));
    *(ushort4*)(ep + ch * 1024 + t * 4) = o;
  }
}

// ---- ET[j][i] = E[i][j]; 64x64 bf16 tiles via LDS.
__global__ void transpose_bf(const unsigned short* __restrict__ E,
                             unsigned short* __restrict__ ET) {
  __shared__ unsigned short tile[64][66];
  const int t = threadIdx.x;
  const int r = t >> 3;
  const int c8 = (t & 7) << 3;
  const size_t i0 = (size_t)blockIdx.y << 6;
  const size_t j0 = (size_t)blockIdx.x << 6;
#pragma unroll
  for (int h = 0; h < 2; ++h) {
    bf16x8 vv = *(const bf16x8*)(E + (i0 + h * 32 + r) * 4096 + j0 + c8);
#pragma unroll
    for (int e = 0; e < 8; ++e) tile[h * 32 + r][c8 + e] = (unsigned short)vv[e];
  }
  __syncthreads();
#pragma unroll
  for (int h = 0; h < 2; ++h) {
    bf16x8 vv;
#pragma unroll
    for (int e = 0; e < 8; ++e) vv[e] = (short)tile[c8 + e][h * 32 + r];
    *(bf16x8*)(ET + (j0 + h * 32 + r) * 4096 + i0 + c8) = vv;
  }
}

// ---- u[i] = exp(c_prev[i])
__global__ void init_u(const float* __restrict__ c_prev, float* __restrict__ u) {
  const int i = blockIdx.x * 256 + threadIdx.x;
  u[i] = exp2f(c_prev[i] * L2E);
}

// ---- out[row] = 1 / sum_j M[row][j]*uin[j]; 1 wave per row, 4 rows/block.
__global__ void recip_mv(const unsigned short* __restrict__ M,
                         const float* __restrict__ uin, float* __restrict__ vout) {
  const int t = threadIdx.x;
  const int l = t & 63, w = t >> 6;
  const int row = (blockIdx.x << 2) + w;
  const unsigned short* mp = M + ((size_t)row << 12);
  float s = 0.f;
#pragma unroll
  for (int ch = 0; ch < 8; ++ch) {
    const int j = (ch << 9) + (l << 3);
    bf16x8 e = *(const bf16x8*)(mp + j);
    const float4 u0 = *(const float4*)(uin + j);
    const float4 u1 = *(const float4*)(uin + j + 4);
    s = fmaf(bf2f(e[0]), u0.x, s);
    s = fmaf(bf2f(e[1]), u0.y, s);
    s = fmaf(bf2f(e[2]), u0.z, s);
    s = fmaf(bf2f(e[3]), u0.w, s);
    s = fmaf(bf2f(e[4]), u1.x, s);
    s = fmaf(bf2f(e[5]), u1.y, s);
    s = fmaf(bf2f(e[6]), u1.z, s);
    s = fmaf(bf2f(e[7]), u1.w, s);
  }
#pragma unroll
  for (int off = 32; off > 0; off >>= 1) s += __shfl_xor(s, off);
  if (l == 0) vout[row] = 1.f / s;
}

// ---- xb[t,j] = bf16(x[t,j] * u[j])
__global__ void scale_x(const float* __restrict__ X, const float* __restrict__ u,
                        unsigned short* __restrict__ Y) {
  const size_t idx = ((size_t)blockIdx.x * 256 + threadIdx.x) * 4;
  const int col = (int)(idx & 4095);
  float4 xv = *(const float4*)(X + idx);
  float4 uu = *(const float4*)(u + col);
  ushort4 o;
  o.x = f2bf(xv.x * uu.x);
  o.y = f2bf(xv.y * uu.y);
  o.z = f2bf(xv.z * uu.z);
  o.w = f2bf(xv.w * uu.w);
  *(ushort4*)(Y + idx) = o;
}

// ---- C[m,n] = v[n] * sum_k A[m,k]*B[n,k]; A [8192,4096], B [4096,4096] bf16.
// 256x256 tile, BK=32, 8 waves (2Mx4N), 4-buffer LDS ring, counted vmcnt(8).
// LDS map (halfwords): A buf b @ [b*8192), row-major 256x32, chunk-XOR swizzle:
//   physical 8-hw chunk of (row, logical c) = c ^ (row&3).
// B buf b @ [32768 + b*8192). Stage: linear LDS dest, inverse-permuted global src.
__global__ __launch_bounds__(512) void gemm_bt(const unsigned short* __restrict__ A,
                                               const unsigned short* __restrict__ B,
                                               const float* __restrict__ vscale,
                                               float* __restrict__ C) {
  __shared__ unsigned short lds[65536];  // 128 KB
  const int t = threadIdx.x;
  const int l = t & 63;
  const int w = t >> 6;          // 0..7
  const int wm = w >> 2, wn = w & 3;

  // XCD-bijective swizzle (512 % 8 == 0) + GROUP_M=4 (4 bm x 16 bn per XCD chunk)
  int pid = blockIdx.x;
  pid = (pid & 7) * 64 + (pid >> 3);
  const int grp = pid >> 6;             // 0..7
  const int rem = pid & 63;
  const int bm = (grp << 2) + (rem & 3);  // 0..31
  const int bn = rem >> 2;                // 0..15
  const int m0 = bm << 8;
  const int n0 = bn << 8;

  // staging: thread t covers (row = r0 + t/4, physical chunk = t&3); the global
  // source is the logical chunk that belongs at that physical slot.
  const int ca = (((t & 3) ^ ((t >> 2) & 3)) << 3);     // ushort offset in [0,32)
  const unsigned short* gA = A + (size_t)(m0 + (t >> 2)) * 4096 + ca;
  const unsigned short* gB = B + (size_t)(n0 + (t >> 2)) * 4096 + ca;

  // ds_read bases (halfwords): physical chunk = logical(l>>4) ^ (row&3 = l&3)
  const int xc = (((l >> 4) ^ (l & 3)) << 3);
  const int aOff = (wm * 128 + (l & 15)) * 32 + xc;
  const int bOff = (wn * 64 + (l & 15)) * 32 + xc;

  auto stageA = [&](int kt) {
    const int b = kt & 3;
    const unsigned short* g = gA + (size_t)kt * 32;
#pragma unroll
    for (int ra = 0; ra < 2; ++ra)
      __builtin_amdgcn_global_load_lds(
          (const __attribute__((address_space(1))) void*)(g + (size_t)ra * 524288),
          (__attribute__((address_space(3))) void*)((char*)lds + b * 16384 + ra * 8192 + w * 1024),
          16, 0, 0);
  };
  auto stageB = [&](int kt) {
    const int b = kt & 3;
    const unsigned short* g = gB + (size_t)kt * 32;
#pragma unroll
    for (int ra = 0; ra < 2; ++ra)
      __builtin_amdgcn_global_load_lds(
          (const __attribute__((address_space(1))) void*)(g + (size_t)ra * 524288),
          (__attribute__((address_space(3))) void*)((char*)lds + 65536 + b * 16384 + ra * 8192 + w * 1024),
          16, 0, 0);
  };

  f32x4 acc[8][4] = {};

  // Prologue: stage K-tiles 0..2 (12 loads); wait for K-tile 0 (8 outstanding).
  stageA(0); stageB(0);
  stageA(1); stageB(1);
  stageA(2); stageB(2);
  asm volatile("s_waitcnt vmcnt(8)" ::: "memory");
  __builtin_amdgcn_s_barrier();

  for (int kt = 0; kt < 128; ++kt) {
    const int buf = kt & 3;
    const unsigned short* aL = lds + buf * 8192 + aOff;
    const unsigned short* bL = lds + 32768 + buf * 8192 + bOff;
    bf16x8 afr[4], bfr[4];

    // ---- phase 0: M-frags 0-3 x N-frags 0-3
#pragma unroll
    for (int i = 0; i < 4; ++i) afr[i] = *(const bf16x8*)(aL + i * 512);
#pragma unroll
    for (int j = 0; j < 4; ++j) bfr[j] = *(const bf16x8*)(bL + j * 512);
    if (kt < 125) stageA(kt + 3);  // overwrites buf (kt-1)&3: reads done last K-tile
    __builtin_amdgcn_s_barrier();
    __builtin_amdgcn_s_setprio(1);
#pragma unroll
    for (int i = 0; i < 4; ++i)
#pragma unroll
      for (int j = 0; j < 4; ++j)
        acc[i][j] = __builtin_amdgcn_mfma_f32_16x16x32_bf16(afr[i], bfr[j], acc[i][j], 0, 0, 0);
    __builtin_amdgcn_s_setprio(0);
    __builtin_amdgcn_s_barrier();

    // ---- phase 1: M-frags 4-7 x N-frags 0-3
#pragma unroll
    for (int i = 0; i < 4; ++i) afr[i] = *(const bf16x8*)(aL + (4 + i) * 512);
    if (kt < 125) stageB(kt + 3);
    __builtin_amdgcn_s_barrier();
    __builtin_amdgcn_s_setprio(1);
#pragma unroll
    for (int i = 0; i < 4; ++i)
#pragma unroll
      for (int j = 0; j < 4; ++j)
        acc[4 + i][j] = __builtin_amdgcn_mfma_f32_16x16x32_bf16(afr[i], bfr[j], acc[4 + i][j], 0, 0, 0);
    __builtin_amdgcn_s_setprio(0);

    // K-tile boundary: ensure buf (kt+1)&3 landed on ALL waves (vmcnt, then barrier).
    if (kt < 125)        asm volatile("s_waitcnt vmcnt(8)" ::: "memory");
    else if (kt == 125)  asm volatile("s_waitcnt vmcnt(4)" ::: "memory");
    else if (kt == 126)  asm volatile("s_waitcnt vmcnt(0)" ::: "memory");
    __builtin_amdgcn_s_barrier();
  }

  // Epilogue: C[m,n] = acc * v[n]
  const int crow = (l >> 4) << 2;
  const int ccol = l & 15;
#pragma unroll
  for (int j = 0; j < 4; ++j) {
    const int colj = n0 + (wn << 6) + (j << 4) + ccol;
    const float vs = vscale[colj];
#pragma unroll
    for (int i = 0; i < 8; ++i) {
      const int rowi = m0 + (wm << 7) + (i << 4) + crow;
#pragma unroll
      for (int q = 0; q < 4; ++q)
        C[((size_t)(rowi + q) << 12) + colj] = acc[i][j][q] * vs;
    }
  }
}

extern "C" void kernel_launch(void* const* d_in, const int* in_sizes, int n_in,
                              void* d_out, int out_size, void* d_ws, size_t ws_size,
                              hipStream_t stream) {
  const float* x      = (const float*)d_in[0];   // [4,2048,4096] f32
  const float* weight = (const float*)d_in[1];   // [4096,4096] f32
  const float* c_prev = (const float*)d_in[3];   // [1,4096] f32; r_prev unused
  float* out = (float*)d_out;

  char* ws = (char*)d_ws;
  float* u = (float*)ws;                                   // 4096 f32
  float* v = (float*)(ws + (16 << 10));                    // 4096 f32
  unsigned short* E  = (unsigned short*)(ws + (64 << 10)); // 33.5 MB
  unsigned short* ET = E + (size_t)4096 * 4096;            // 33.5 MB (dead after iters)
  unsigned short* xb = ET;                                 // xb overlays ET (67 MB)

  prep_e<<<4096, 256, 0, stream>>>(weight, E);
  transpose_bf<<<dim3(64, 64), 256, 0, stream>>>(E, ET);
  init_u<<<16, 256, 0, stream>>>(c_prev, u);

  for (int it = 0; it < 10; ++it) {
    recip_mv<<<1024, 256, 0, stream>>>(E, u, v);   // v = 1/(E u)
    recip_mv<<<1024, 256, 0, stream>>>(ET, v, u);  // u = 1/(E^T v)
  }

  scale_x<<<32768, 256, 0, stream>>>(x, u, xb);    // xb = bf16(x * u), kills ET

  gemm_bt<<<512, 512, 0, stream>>>(xb, E, v, out);
}

// Round 4
// 449.079 us; speedup vs baseline: 3.2152x; 1.0231x over previous
//
#include <hip/hip_runtime.h>

// WarmStartSinkhornLinear on MI355X — round 4.
// Scaling-form Sinkhorn (unchanged) + deep-pipelined 256x256 bf16 MFMA GEMM.
// Round-4 change: corrected LDS chunk-XOR swizzle f(row) = (row>>1)&3 so each
// 8-lane quantum of ds_read_b128 covers all 32 banks exactly once (the old
// f(row)=row&3 left 2-way conflicts in every octet -> 2.5e7 SQ_LDS_BANK_CONFLICT).

#define L2E 1.44269504088896340736f

typedef __attribute__((ext_vector_type(8))) short bf16x8;
typedef __attribute__((ext_vector_type(4))) float f32x4;

__device__ __forceinline__ unsigned short f2bf(float x) {
  unsigned u = __float_as_uint(x);
  u += 0x7fffu + ((u >> 16) & 1u);  // RNE
  return (unsigned short)(u >> 16);
}
__device__ __forceinline__ float bf2f(short x) {
  return __uint_as_float(((unsigned)(unsigned short)x) << 16);
}

// ---- E[row,:] = bf16(exp(10*W[row,:] - rowmax)); one block per row.
__global__ void prep_e(const float* __restrict__ W, unsigned short* __restrict__ E) {
  const int row = blockIdx.x;
  const int t = threadIdx.x;
  const float* wp = W + ((size_t)row << 12);
  float v[16];
  float m = -3.4e38f;
#pragma unroll
  for (int ch = 0; ch < 4; ++ch) {
    float4 wv = *(const float4*)(wp + ch * 1024 + t * 4);
    float a0 = 10.f * wv.x, a1 = 10.f * wv.y, a2 = 10.f * wv.z, a3 = 10.f * wv.w;
    v[ch * 4 + 0] = a0; v[ch * 4 + 1] = a1; v[ch * 4 + 2] = a2; v[ch * 4 + 3] = a3;
    m = fmaxf(m, fmaxf(fmaxf(a0, a1), fmaxf(a2, a3)));
  }
#pragma unroll
  for (int off = 32; off > 0; off >>= 1) m = fmaxf(m, __shfl_xor(m, off));
  __shared__ float sm[4];
  if ((t & 63) == 0) sm[t >> 6] = m;
  __syncthreads();
  m = fmaxf(fmaxf(sm[0], sm[1]), fmaxf(sm[2], sm[3]));
  unsigned short* ep = E + ((size_t)row << 12);
#pragma unroll
  for (int ch = 0; ch < 4; ++ch) {
    ushort4 o;
    o.x = f2bf(exp2f((v[ch * 4 + 0] - m) * L2E));
    o.y = f2bf(exp2f((v[ch * 4 + 1] - m) * L2E));
    o.z = f2bf(exp2f((v[ch * 4 + 2] - m) * L2E));
    o.w = f2bf(exp2f((v[ch * 4 + 3] - m) * L2E));
    *(ushort4*)(ep + ch * 1024 + t * 4) = o;
  }
}

// ---- ET[j][i] = E[i][j]; 64x64 bf16 tiles via LDS.
__global__ void transpose_bf(const unsigned short* __restrict__ E,
                             unsigned short* __restrict__ ET) {
  __shared__ unsigned short tile[64][66];
  const int t = threadIdx.x;
  const int r = t >> 3;
  const int c8 = (t & 7) << 3;
  const size_t i0 = (size_t)blockIdx.y << 6;
  const size_t j0 = (size_t)blockIdx.x << 6;
#pragma unroll
  for (int h = 0; h < 2; ++h) {
    bf16x8 vv = *(const bf16x8*)(E + (i0 + h * 32 + r) * 4096 + j0 + c8);
#pragma unroll
    for (int e = 0; e < 8; ++e) tile[h * 32 + r][c8 + e] = (unsigned short)vv[e];
  }
  __syncthreads();
#pragma unroll
  for (int h = 0; h < 2; ++h) {
    bf16x8 vv;
#pragma unroll
    for (int e = 0; e < 8; ++e) vv[e] = (short)tile[c8 + e][h * 32 + r];
    *(bf16x8*)(ET + (j0 + h * 32 + r) * 4096 + i0 + c8) = vv;
  }
}

// ---- u[i] = exp(c_prev[i])
__global__ void init_u(const float* __restrict__ c_prev, float* __restrict__ u) {
  const int i = blockIdx.x * 256 + threadIdx.x;
  u[i] = exp2f(c_prev[i] * L2E);
}

// ---- out[row] = 1 / sum_j M[row][j]*uin[j]; 1 wave per row, 4 rows/block.
__global__ void recip_mv(const unsigned short* __restrict__ M,
                         const float* __restrict__ uin, float* __restrict__ vout) {
  const int t = threadIdx.x;
  const int l = t & 63, w = t >> 6;
  const int row = (blockIdx.x << 2) + w;
  const unsigned short* mp = M + ((size_t)row << 12);
  float s = 0.f;
#pragma unroll
  for (int ch = 0; ch < 8; ++ch) {
    const int j = (ch << 9) + (l << 3);
    bf16x8 e = *(const bf16x8*)(mp + j);
    const float4 u0 = *(const float4*)(uin + j);
    const float4 u1 = *(const float4*)(uin + j + 4);
    s = fmaf(bf2f(e[0]), u0.x, s);
    s = fmaf(bf2f(e[1]), u0.y, s);
    s = fmaf(bf2f(e[2]), u0.z, s);
    s = fmaf(bf2f(e[3]), u0.w, s);
    s = fmaf(bf2f(e[4]), u1.x, s);
    s = fmaf(bf2f(e[5]), u1.y, s);
    s = fmaf(bf2f(e[6]), u1.z, s);
    s = fmaf(bf2f(e[7]), u1.w, s);
  }
#pragma unroll
  for (int off = 32; off > 0; off >>= 1) s += __shfl_xor(s, off);
  if (l == 0) vout[row] = 1.f / s;
}

// ---- xb[t,j] = bf16(x[t,j] * u[j])
__global__ void scale_x(const float* __restrict__ X, const float* __restrict__ u,
                        unsigned short* __restrict__ Y) {
  const size_t idx = ((size_t)blockIdx.x * 256 + threadIdx.x) * 4;
  const int col = (int)(idx & 4095);
  float4 xv = *(const float4*)(X + idx);
  float4 uu = *(const float4*)(u + col);
  ushort4 o;
  o.x = f2bf(xv.x * uu.x);
  o.y = f2bf(xv.y * uu.y);
  o.z = f2bf(xv.z * uu.z);
  o.w = f2bf(xv.w * uu.w);
  *(ushort4*)(Y + idx) = o;
}

// ---- C[m,n] = v[n] * sum_k A[m,k]*B[n,k]; A [8192,4096], B [4096,4096] bf16.
// 256x256 tile, BK=32, 8 waves (2Mx4N), 4-buffer LDS ring, counted vmcnt.
// LDS map (halfwords): row-major 256x32 per buffer; physical 8-hw chunk of
// (row, logical c) = c ^ ((row>>1)&3). Stage: linear LDS dest, inverse-permuted
// global source (same involution).
__global__ __launch_bounds__(512) void gemm_bt(const unsigned short* __restrict__ A,
                                               const unsigned short* __restrict__ B,
                                               const float* __restrict__ vscale,
                                               float* __restrict__ C) {
  __shared__ unsigned short lds[65536];  // 128 KB
  const int t = threadIdx.x;
  const int l = t & 63;
  const int w = t >> 6;          // 0..7
  const int wm = w >> 2, wn = w & 3;

  // XCD-bijective swizzle (512 % 8 == 0) + GROUP_M=4 (4 bm x 16 bn per XCD chunk)
  int pid = blockIdx.x;
  pid = (pid & 7) * 64 + (pid >> 3);
  const int grp = pid >> 6;             // 0..7
  const int rem = pid & 63;
  const int bm = (grp << 2) + (rem & 3);  // 0..31
  const int bn = rem >> 2;                // 0..15
  const int m0 = bm << 8;
  const int n0 = bn << 8;

  // staging: thread t writes LDS row (t>>2), physical chunk (t&3); fetch the
  // logical chunk that belongs there: logical = (t&3) ^ f(row), f(r)=(r>>1)&3.
  const int ca = (((t & 3) ^ ((t >> 3) & 3)) << 3);     // ushort offset in [0,32)
  const unsigned short* gA = A + (size_t)(m0 + (t >> 2)) * 4096 + ca;
  const unsigned short* gB = B + (size_t)(n0 + (t >> 2)) * 4096 + ca;

  // ds_read: lane l wants logical chunk (l>>4) of row (l&15) -> physical =
  // (l>>4) ^ ((l>>1)&3). Fragment bases are multiples of 16 rows, so f depends
  // only on l&15. Each 8-lane octet covers all 32 banks exactly once.
  const int xc = (((l >> 4) ^ ((l >> 1) & 3)) << 3);
  const int aOff = (wm * 128 + (l & 15)) * 32 + xc;
  const int bOff = (wn * 64 + (l & 15)) * 32 + xc;

  auto stageA = [&](int kt) {
    const int b = kt & 3;
    const unsigned short* g = gA + (size_t)kt * 32;
#pragma unroll
    for (int ra = 0; ra < 2; ++ra)
      __builtin_amdgcn_global_load_lds(
          (const __attribute__((address_space(1))) void*)(g + (size_t)ra * 524288),
          (__attribute__((address_space(3))) void*)((char*)lds + b * 16384 + ra * 8192 + w * 1024),
          16, 0, 0);
  };
  auto stageB = [&](int kt) {
    const int b = kt & 3;
    const unsigned short* g = gB + (size_t)kt * 32;
#pragma unroll
    for (int ra = 0; ra < 2; ++ra)
      __builtin_amdgcn_global_load_lds(
          (const __attribute__((address_space(1))) void*)(g + (size_t)ra * 524288),
          (__attribute__((address_space(3))) void*)((char*)lds + 65536 + b * 16384 + ra * 8192 + w * 1024),
          16, 0, 0);
  };

  f32x4 acc[8][4] = {};

  // Prologue: stage K-tiles 0..2 (12 per-wave loads); wait for K-tile 0.
  stageA(0); stageB(0);
  stageA(1); stageB(1);
  stageA(2); stageB(2);
  asm volatile("s_waitcnt vmcnt(8)" ::: "memory");
  __builtin_amdgcn_s_barrier();

  for (int kt = 0; kt < 128; ++kt) {
    const int buf = kt & 3;
    const unsigned short* aL = lds + buf * 8192 + aOff;
    const unsigned short* bL = lds + 32768 + buf * 8192 + bOff;
    bf16x8 afr[4], bfr[4];

    // ---- phase 0: M-frags 0-3 x N-frags 0-3
#pragma unroll
    for (int i = 0; i < 4; ++i) afr[i] = *(const bf16x8*)(aL + i * 512);
#pragma unroll
    for (int j = 0; j < 4; ++j) bfr[j] = *(const bf16x8*)(bL + j * 512);
    if (kt < 125) stageA(kt + 3);  // overwrites buf (kt-1)&3: reads done last K-tile
    __builtin_amdgcn_s_barrier();
    __builtin_amdgcn_s_setprio(1);
#pragma unroll
    for (int i = 0; i < 4; ++i)
#pragma unroll
      for (int j = 0; j < 4; ++j)
        acc[i][j] = __builtin_amdgcn_mfma_f32_16x16x32_bf16(afr[i], bfr[j], acc[i][j], 0, 0, 0);
    __builtin_amdgcn_s_setprio(0);
    __builtin_amdgcn_s_barrier();

    // ---- phase 1: M-frags 4-7 x N-frags 0-3
#pragma unroll
    for (int i = 0; i < 4; ++i) afr[i] = *(const bf16x8*)(aL + (4 + i) * 512);
    if (kt < 125) stageB(kt + 3);
    __builtin_amdgcn_s_barrier();
    __builtin_amdgcn_s_setprio(1);
#pragma unroll
    for (int i = 0; i < 4; ++i)
#pragma unroll
      for (int j = 0; j < 4; ++j)
        acc[4 + i][j] = __builtin_amdgcn_mfma_f32_16x16x32_bf16(afr[i], bfr[j], acc[4 + i][j], 0, 0, 0);
    __builtin_amdgcn_s_setprio(0);

    // K-tile boundary: ensure buf (kt+1)&3 landed on ALL waves (vmcnt, then barrier).
    if (kt < 125)        asm volatile("s_waitcnt vmcnt(8)" ::: "memory");
    else if (kt == 125)  asm volatile("s_waitcnt vmcnt(4)" ::: "memory");
    else if (kt == 126)  asm volatile("s_waitcnt vmcnt(0)" ::: "memory");
    __builtin_amdgcn_s_barrier();
  }

  // Epilogue: C[m,n] = acc * v[n]
  const int crow = (l >> 4) << 2;
  const int ccol = l & 15;
#pragma unroll
  for (int j = 0; j < 4; ++j) {
    const int colj = n0 + (wn << 6) + (j << 4) + ccol;
    const float vs = vscale[colj];
#pragma unroll
    for (int i = 0; i < 8; ++i) {
      const int rowi = m0 + (wm << 7) + (i << 4) + crow;
#pragma unroll
      for (int q = 0; q < 4; ++q)
        C[((size_t)(rowi + q) << 12) + colj] = acc[i][j][q] * vs;
    }
  }
}

extern "C" void kernel_launch(void* const* d_in, const int* in_sizes, int n_in,
                              void* d_out, int out_size, void* d_ws, size_t ws_size,
                              hipStream_t stream) {
  const float* x      = (const float*)d_in[0];   // [4,2048,4096] f32
  const float* weight = (const float*)d_in[1];   // [4096,4096] f32
  const float* c_prev = (const float*)d_in[3];   // [1,4096] f32; r_prev unused
  float* out = (float*)d_out;

  char* ws = (char*)d_ws;
  float* u = (float*)ws;                                   // 4096 f32
  float* v = (float*)(ws + (16 << 10));                    // 4096 f32
  unsigned short* E  = (unsigned short*)(ws + (64 << 10)); // 33.5 MB
  unsigned short* ET = E + (size_t)4096 * 4096;            // 33.5 MB (dead after iters)
  unsigned short* xb = ET;                                 // xb overlays ET (67 MB)

  prep_e<<<4096, 256, 0, stream>>>(weight, E);
  transpose_bf<<<dim3(64, 64), 256, 0, stream>>>(E, ET);
  init_u<<<16, 256, 0, stream>>>(c_prev, u);

  for (int it = 0; it < 10; ++it) {
    recip_mv<<<1024, 256, 0, stream>>>(E, u, v);   // v = 1/(E u)
    recip_mv<<<1024, 256, 0, stream>>>(ET, v, u);  // u = 1/(E^T v)
  }

  scale_x<<<32768, 256, 0, stream>>>(x, u, xb);    // xb = bf16(x * u), kills ET

  gemm_bt<<<512, 512, 0, stream>>>(xb, E, v, out);
}

// Round 5
// 444.882 us; speedup vs baseline: 3.2455x; 1.0094x over previous
//
#include <hip/hip_runtime.h>

// WarmStartSinkhornLinear on MI355X — round 5.
// Scaling-form Sinkhorn (unchanged) + 256x256 bf16 MFMA GEMM with
// one-phase-ahead register prefetch: ds_reads issued in phase p are consumed
// in phase p+1 (ping-pong frag regs), vmcnt(6) mid-K-tile so the next
// buffer is ready for the cross-tile prefetch. 4-buffer LDS ring, BK=32,
// conflict-free chunk-XOR swizzle f(row)=(row>>1)&3, XCD-bijective block map.

#define L2E 1.44269504088896340736f

typedef __attribute__((ext_vector_type(8))) short bf16x8;
typedef __attribute__((ext_vector_type(4))) float f32x4;

__device__ __forceinline__ unsigned short f2bf(float x) {
  unsigned u = __float_as_uint(x);
  u += 0x7fffu + ((u >> 16) & 1u);  // RNE
  return (unsigned short)(u >> 16);
}
__device__ __forceinline__ float bf2f(short x) {
  return __uint_as_float(((unsigned)(unsigned short)x) << 16);
}

// ---- E[row,:] = bf16(exp(10*W[row,:] - rowmax)); one block per row.
__global__ void prep_e(const float* __restrict__ W, unsigned short* __restrict__ E) {
  const int row = blockIdx.x;
  const int t = threadIdx.x;
  const float* wp = W + ((size_t)row << 12);
  float v[16];
  float m = -3.4e38f;
#pragma unroll
  for (int ch = 0; ch < 4; ++ch) {
    float4 wv = *(const float4*)(wp + ch * 1024 + t * 4);
    float a0 = 10.f * wv.x, a1 = 10.f * wv.y, a2 = 10.f * wv.z, a3 = 10.f * wv.w;
    v[ch * 4 + 0] = a0; v[ch * 4 + 1] = a1; v[ch * 4 + 2] = a2; v[ch * 4 + 3] = a3;
    m = fmaxf(m, fmaxf(fmaxf(a0, a1), fmaxf(a2, a3)));
  }
#pragma unroll
  for (int off = 32; off > 0; off >>= 1) m = fmaxf(m, __shfl_xor(m, off));
  __shared__ float sm[4];
  if ((t & 63) == 0) sm[t >> 6] = m;
  __syncthreads();
  m = fmaxf(fmaxf(sm[0], sm[1]), fmaxf(sm[2], sm[3]));
  unsigned short* ep = E + ((size_t)row << 12);
#pragma unroll
  for (int ch = 0; ch < 4; ++ch) {
    ushort4 o;
    o.x = f2bf(exp2f((v[ch * 4 + 0] - m) * L2E));
    o.y = f2bf(exp2f((v[ch * 4 + 1] - m) * L2E));
    o.z = f2bf(exp2f((v[ch * 4 + 2] - m) * L2E));
    o.w = f2bf(exp2f((v[ch * 4 + 3] - m) * L2E));
    *(ushort4*)(ep + ch * 1024 + t * 4) = o;
  }
}

// ---- ET[j][i] = E[i][j]; 64x64 bf16 tiles via LDS.
__global__ void transpose_bf(const unsigned short* __restrict__ E,
                             unsigned short* __restrict__ ET) {
  __shared__ unsigned short tile[64][66];
  const int t = threadIdx.x;
  const int r = t >> 3;
  const int c8 = (t & 7) << 3;
  const size_t i0 = (size_t)blockIdx.y << 6;
  const size_t j0 = (size_t)blockIdx.x << 6;
#pragma unroll
  for (int h = 0; h < 2; ++h) {
    bf16x8 vv = *(const bf16x8*)(E + (i0 + h * 32 + r) * 4096 + j0 + c8);
#pragma unroll
    for (int e = 0; e < 8; ++e) tile[h * 32 + r][c8 + e] = (unsigned short)vv[e];
  }
  __syncthreads();
#pragma unroll
  for (int h = 0; h < 2; ++h) {
    bf16x8 vv;
#pragma unroll
    for (int e = 0; e < 8; ++e) vv[e] = (short)tile[c8 + e][h * 32 + r];
    *(bf16x8*)(ET + (j0 + h * 32 + r) * 4096 + i0 + c8) = vv;
  }
}

// ---- u[i] = exp(c_prev[i])
__global__ void init_u(const float* __restrict__ c_prev, float* __restrict__ u) {
  const int i = blockIdx.x * 256 + threadIdx.x;
  u[i] = exp2f(c_prev[i] * L2E);
}

// ---- out[row] = 1 / sum_j M[row][j]*uin[j]; 1 wave per row, 4 rows/block.
__global__ void recip_mv(const unsigned short* __restrict__ M,
                         const float* __restrict__ uin, float* __restrict__ vout) {
  const int t = threadIdx.x;
  const int l = t & 63, w = t >> 6;
  const int row = (blockIdx.x << 2) + w;
  const unsigned short* mp = M + ((size_t)row << 12);
  float s = 0.f;
#pragma unroll
  for (int ch = 0; ch < 8; ++ch) {
    const int j = (ch << 9) + (l << 3);
    bf16x8 e = *(const bf16x8*)(mp + j);
    const float4 u0 = *(const float4*)(uin + j);
    const float4 u1 = *(const float4*)(uin + j + 4);
    s = fmaf(bf2f(e[0]), u0.x, s);
    s = fmaf(bf2f(e[1]), u0.y, s);
    s = fmaf(bf2f(e[2]), u0.z, s);
    s = fmaf(bf2f(e[3]), u0.w, s);
    s = fmaf(bf2f(e[4]), u1.x, s);
    s = fmaf(bf2f(e[5]), u1.y, s);
    s = fmaf(bf2f(e[6]), u1.z, s);
    s = fmaf(bf2f(e[7]), u1.w, s);
  }
#pragma unroll
  for (int off = 32; off > 0; off >>= 1) s += __shfl_xor(s, off);
  if (l == 0) vout[row] = 1.f / s;
}

// ---- xb[t,j] = bf16(x[t,j] * u[j])
__global__ void scale_x(const float* __restrict__ X, const float* __restrict__ u,
                        unsigned short* __restrict__ Y) {
  const size_t idx = ((size_t)blockIdx.x * 256 + threadIdx.x) * 4;
  const int col = (int)(idx & 4095);
  float4 xv = *(const float4*)(X + idx);
  float4 uu = *(const float4*)(u + col);
  ushort4 o;
  o.x = f2bf(xv.x * uu.x);
  o.y = f2bf(xv.y * uu.y);
  o.z = f2bf(xv.z * uu.z);
  o.w = f2bf(xv.w * uu.w);
  *(ushort4*)(Y + idx) = o;
}

// ---- C[m,n] = v[n] * sum_k A[m,k]*B[n,k]; A [8192,4096], B [4096,4096] bf16.
// 256x256 tile, BK=32, 8 waves (2Mx4N), 4-buffer LDS ring.
// Phase schedule (per K-tile kt):
//  pA: read A-frags4-7(kt) | stage A(kt+3) | vmcnt(6) | bar | MFMA cur0-3 x curB | bar
//  pB: prefetch A0-3,B0-3(kt+1) into ping-pong regs | stage B(kt+3) | bar |
//      MFMA h x curB | bar
// vmcnt(6) at pA leaves {A,B}(kt+2),A(kt+3) in flight; guarantees buf kt+1
// landed on all waves (with the following barrier) before pB's prefetch.
__global__ __launch_bounds__(512, 2) void gemm_bt(const unsigned short* __restrict__ A,
                                                  const unsigned short* __restrict__ B,
                                                  const float* __restrict__ vscale,
                                                  float* __restrict__ C) {
  __shared__ unsigned short lds[65536];  // 128 KB
  const int t = threadIdx.x;
  const int l = t & 63;
  const int w = t >> 6;          // 0..7
  const int wm = w >> 2, wn = w & 3;

  // XCD-bijective swizzle (512 % 8 == 0) + GROUP_M=4
  int pid = blockIdx.x;
  pid = (pid & 7) * 64 + (pid >> 3);
  const int grp = pid >> 6;
  const int rem = pid & 63;
  const int bm = (grp << 2) + (rem & 3);
  const int bn = rem >> 2;
  const int m0 = bm << 8;
  const int n0 = bn << 8;

  // staging: thread t writes LDS row (t>>2), physical chunk (t&3); fetch the
  // logical chunk that belongs there: logical = (t&3) ^ f(row), f(r)=(r>>1)&3.
  const int ca = (((t & 3) ^ ((t >> 3) & 3)) << 3);
  const unsigned short* gA = A + (size_t)(m0 + (t >> 2)) * 4096 + ca;
  const unsigned short* gB = B + (size_t)(n0 + (t >> 2)) * 4096 + ca;

  // ds_read: lane l, logical chunk (l>>4) of row (l&15) -> physical =
  // (l>>4) ^ ((l>>1)&3). Conflict-free: each 8-lane octet covers all 32 banks.
  const int xc = (((l >> 4) ^ ((l >> 1) & 3)) << 3);
  const int aOff = (wm * 128 + (l & 15)) * 32 + xc;
  const int bOff = (wn * 64 + (l & 15)) * 32 + xc;

  auto stageA = [&](int kt) {
    const int b = kt & 3;
    const unsigned short* g = gA + (size_t)kt * 32;
#pragma unroll
    for (int ra = 0; ra < 2; ++ra)
      __builtin_amdgcn_global_load_lds(
          (const __attribute__((address_space(1))) void*)(g + (size_t)ra * 524288),
          (__attribute__((address_space(3))) void*)((char*)lds + b * 16384 + ra * 8192 + w * 1024),
          16, 0, 0);
  };
  auto stageB = [&](int kt) {
    const int b = kt & 3;
    const unsigned short* g = gB + (size_t)kt * 32;
#pragma unroll
    for (int ra = 0; ra < 2; ++ra)
      __builtin_amdgcn_global_load_lds(
          (const __attribute__((address_space(1))) void*)(g + (size_t)ra * 524288),
          (__attribute__((address_space(3))) void*)((char*)lds + 65536 + b * 16384 + ra * 8192 + w * 1024),
          16, 0, 0);
  };

  f32x4 acc[8][4] = {};

  // Prologue: stage K-tiles 0..2; wait for K-tile 0 (8 = tiles 1,2 in flight).
  stageA(0); stageB(0);
  stageA(1); stageB(1);
  stageA(2); stageB(2);
  asm volatile("s_waitcnt vmcnt(8)" ::: "memory");
  __builtin_amdgcn_s_barrier();

  bf16x8 cA[4], cB[4], nA[4], nB[4], hfr[4];
#pragma unroll
  for (int i = 0; i < 4; ++i) cA[i] = *(const bf16x8*)(lds + aOff + i * 512);
#pragma unroll
  for (int j = 0; j < 4; ++j) cB[j] = *(const bf16x8*)(lds + 32768 + bOff + j * 512);

#define PHASE_PAIR(KT, CA, CB, NA, NB)                                            \
  {                                                                               \
    const int kt_ = (KT);                                                         \
    const int buf_ = kt_ & 3;                                                     \
    const unsigned short* aL = lds + buf_ * 8192 + aOff;                          \
    const unsigned short* bL = lds + 32768 + buf_ * 8192 + bOff;                  \
    /* pA: h-reads for this tile's second quad; stage A(kt+3); vmcnt; MFMA q0 */  \
    _Pragma("unroll")                                                             \
    for (int i = 0; i < 4; ++i) hfr[i] = *(const bf16x8*)(aL + (4 + i) * 512);    \
    if (kt_ <= 124) stageA(kt_ + 3);                                              \
    if (kt_ <= 124)      asm volatile("s_waitcnt vmcnt(6)" ::: "memory");         \
    else if (kt_ == 125) asm volatile("s_waitcnt vmcnt(4)" ::: "memory");         \
    else                 asm volatile("s_waitcnt vmcnt(0)" ::: "memory");         \
    __builtin_amdgcn_sched_barrier(0);                                            \
    __builtin_amdgcn_s_barrier();                                                 \
    __builtin_amdgcn_s_setprio(1);                                                \
    _Pragma("unroll")                                                             \
    for (int i = 0; i < 4; ++i)                                                   \
      _Pragma("unroll")                                                           \
      for (int j = 0; j < 4; ++j)                                                 \
        acc[i][j] = __builtin_amdgcn_mfma_f32_16x16x32_bf16(CA[i], CB[j],         \
                                                            acc[i][j], 0, 0, 0); \
    __builtin_amdgcn_s_setprio(0);                                                \
    __builtin_amdgcn_s_barrier();                                                 \
    /* pB: prefetch next tile's frags (buf kt+1 is ready); stage B; MFMA q1 */    \
    if (kt_ <= 126) {                                                             \
      const unsigned short* aN = lds + ((kt_ + 1) & 3) * 8192 + aOff;             \
      const unsigned short* bN = lds + 32768 + ((kt_ + 1) & 3) * 8192 + bOff;     \
      _Pragma("unroll")                                                           \
      for (int i = 0; i < 4; ++i) NA[i] = *(const bf16x8*)(aN + i * 512);         \
      _Pragma("unroll")                                                           \
      for (int j = 0; j < 4; ++j) NB[j] = *(const bf16x8*)(bN + j * 512);         \
    }                                                                             \
    if (kt_ <= 124) stageB(kt_ + 3);                                              \
    __builtin_amdgcn_sched_barrier(0);                                            \
    __builtin_amdgcn_s_barrier();                                                 \
    __builtin_amdgcn_s_setprio(1);                                                \
    _Pragma("unroll")                                                             \
    for (int i = 0; i < 4; ++i)                                                   \
      _Pragma("unroll")                                                           \
      for (int j = 0; j < 4; ++j)                                                 \
        acc[4 + i][j] = __builtin_amdgcn_mfma_f32_16x16x32_bf16(hfr[i], CB[j],    \
                                                                acc[4 + i][j],   \
                                                                0, 0, 0);         \
    __builtin_amdgcn_s_setprio(0);                                                \
    __builtin_amdgcn_s_barrier();                                                 \
  }

  for (int kt = 0; kt < 128; kt += 2) {
    PHASE_PAIR(kt, cA, cB, nA, nB)
    PHASE_PAIR(kt + 1, nA, nB, cA, cB)
  }
#undef PHASE_PAIR

  // Epilogue: C[m,n] = acc * v[n]
  const int crow = (l >> 4) << 2;
  const int ccol = l & 15;
#pragma unroll
  for (int j = 0; j < 4; ++j) {
    const int colj = n0 + (wn << 6) + (j << 4) + ccol;
    const float vs = vscale[colj];
#pragma unroll
    for (int i = 0; i < 8; ++i) {
      const int rowi = m0 + (wm << 7) + (i << 4) + crow;
#pragma unroll
      for (int q = 0; q < 4; ++q)
        C[((size_t)(rowi + q) << 12) + colj] = acc[i][j][q] * vs;
    }
  }
}

extern "C" void kernel_launch(void* const* d_in, const int* in_sizes, int n_in,
                              void* d_out, int out_size, void* d_ws, size_t ws_size,
                              hipStream_t stream) {
  const float* x      = (const float*)d_in[0];   // [4,2048,4096] f32
  const float* weight = (const float*)d_in[1];   // [4096,4096] f32
  const float* c_prev = (const float*)d_in[3];   // [1,4096] f32; r_prev unused
  float* out = (float*)d_out;

  char* ws = (char*)d_ws;
  float* u = (float*)ws;                                   // 4096 f32
  float* v = (float*)(ws + (16 << 10));                    // 4096 f32
  unsigned short* E  = (unsigned short*)(ws + (64 << 10)); // 33.5 MB
  unsigned short* ET = E + (size_t)4096 * 4096;            // 33.5 MB (dead after iters)
  unsigned short* xb = ET;                                 // xb overlays ET (67 MB)

  prep_e<<<4096, 256, 0, stream>>>(weight, E);
  transpose_bf<<<dim3(64, 64), 256, 0, stream>>>(E, ET);
  init_u<<<16, 256, 0, stream>>>(c_prev, u);

  for (int it = 0; it < 10; ++it) {
    recip_mv<<<1024, 256, 0, stream>>>(E, u, v);   // v = 1/(E u)
    recip_mv<<<1024, 256, 0, stream>>>(ET, v, u);  // u = 1/(E^T v)
  }

  scale_x<<<32768, 256, 0, stream>>>(x, u, xb);    // xb = bf16(x * u), kills ET

  gemm_bt<<<512, 512, 0, stream>>>(xb, E, v, out);
}